// Round 1
// baseline (2573.973 us; speedup 1.0000x reference)
//
#include <hip/hip_runtime.h>
#include <cstdint>
#include <cstddef>

#define DD   512
#define NTOK 32768
#define NE   8
#define BM   64
#define BN   64
#define BK   16

// ---------------- routing: gates -> top2 -> softmax weights ----------------
__global__ void route_kernel(const float* __restrict__ x,
                             const float* __restrict__ Wg,
                             const float* __restrict__ bg,
                             int t0, int T,
                             int* __restrict__ counts,
                             int* __restrict__ eids,
                             float* __restrict__ wts) {
    int i = blockIdx.x * blockDim.x + threadIdx.x;
    if (i >= T) return;
    int n = t0 + i;
    const float* xr = x + (size_t)n * DD + (DD - 3);
    float x0 = xr[0], x1 = xr[1], x2 = xr[2];
    float g[NE];
#pragma unroll
    for (int e = 0; e < NE; e++)
        g[e] = x0 * Wg[e] + x1 * Wg[NE + e] + x2 * Wg[2 * NE + e] + bg[e];
    // top-1 (ties -> lowest index, strict >)
    int e0 = 0; float v0 = g[0];
#pragma unroll
    for (int e = 1; e < NE; e++) if (g[e] > v0) { v0 = g[e]; e0 = e; }
    // top-2
    int e1 = -1; float v1 = -3.0e38f;
#pragma unroll
    for (int e = 0; e < NE; e++) if (e != e0 && g[e] > v1) { v1 = g[e]; e1 = e; }
    float t = expf(v1 - v0);           // <= 1
    float s = 1.0f / (1.0f + t);
    eids[2 * i]     = e0;
    eids[2 * i + 1] = e1;
    wts[2 * i]      = s;
    wts[2 * i + 1]  = t * s;
    atomicAdd(&counts[e0], 1);
    atomicAdd(&counts[e1], 1);
}

// ---------------- padded prefix sum over expert counts ----------------
__global__ void offsets_kernel(const int* __restrict__ counts,
                               int* __restrict__ off,
                               int* __restrict__ cursor) {
    if (threadIdx.x == 0) {
        int acc = 0;
        for (int e = 0; e < NE; e++) {
            off[e] = acc;
            cursor[e] = acc;
            acc += (counts[e] + 63) & ~63;   // pad each segment to 64 rows
        }
        off[NE] = acc;
    }
}

// ---------------- scatter token ids into per-expert segments ----------------
__global__ void scatter_kernel(int t0, int T,
                               const int* __restrict__ eids,
                               int* __restrict__ cursor,
                               int* __restrict__ list_token,
                               int* __restrict__ posl) {
    int i = blockIdx.x * blockDim.x + threadIdx.x;
    if (i >= T) return;
#pragma unroll
    for (int k = 0; k < 2; k++) {
        int e = eids[2 * i + k];
        int p = atomicAdd(&cursor[e], 1);
        list_token[p] = t0 + i;
        posl[2 * i + k] = p;
    }
}

// ---------------- tiled fp32 GEMM: C = act(A @ W + b), per-expert W ----------------
// A rows grouped into per-expert segments (block never straddles experts).
template <bool GATHER, bool RELU>
__global__ __launch_bounds__(256) void mlp_gemm(
    const float* __restrict__ A,            // x (GATHER) or h buffer
    const int* __restrict__ list_token,     // used when GATHER
    const float* __restrict__ Wptr,         // weight base for this layer
    int westride,                           // per-expert weight stride (elems)
    const float* __restrict__ bptr,         // bias base for this layer
    int bestride,                           // per-expert bias stride (elems)
    const int* __restrict__ off,            // off[0..8]; off[8] = total rows
    float* __restrict__ Cout)
{
    int rb = blockIdx.x * BM;
    if (rb >= off[NE]) return;
    int e = 0;
#pragma unroll
    for (int q = 1; q < NE; q++) if (rb >= off[q]) e = q;
    const float* W    = Wptr + (size_t)e * westride;   // [512][512] row-major (k,n)
    const float* bias = bptr + (size_t)e * bestride;
    int cb = blockIdx.y * BN;

    __shared__ __align__(16) float As[BK][BM + 4];
    __shared__ __align__(16) float Bs[BK][BN + 4];

    int tid = threadIdx.x;
    // A-load mapping: 4 lanes per row, float4 each -> 64 rows x 16 k
    int am = tid >> 2;
    int ak = (tid & 3) << 2;
    const float* Arow;
    bool avalid;
    if (GATHER) {
        int r = list_token[rb + am];
        avalid = (r >= 0);
        Arow = A + (avalid ? (size_t)r * DD : 0);
    } else {
        avalid = true;
        Arow = A + (size_t)(rb + am) * DD;
    }
    // B-load mapping: 16 lanes per k-row, float4 each -> 16 k x 64 n
    int bn = (tid & 15) << 2;
    int bk = tid >> 4;
    const float* Bp = W + (size_t)bk * DD + cb + bn;

    int tx = tid & 15, ty = tid >> 4;
    float acc[4][4];
#pragma unroll
    for (int i = 0; i < 4; i++)
#pragma unroll
        for (int j = 0; j < 4; j++) acc[i][j] = 0.f;

    for (int k0 = 0; k0 < DD; k0 += BK) {
        float4 av = make_float4(0.f, 0.f, 0.f, 0.f);
        if (avalid) av = *(const float4*)(Arow + k0 + ak);
        float4 bv = *(const float4*)(Bp + (size_t)k0 * DD);
        __syncthreads();
        As[ak + 0][am] = av.x;
        As[ak + 1][am] = av.y;
        As[ak + 2][am] = av.z;
        As[ak + 3][am] = av.w;
        *(float4*)&Bs[bk][bn] = bv;
        __syncthreads();
#pragma unroll
        for (int kk = 0; kk < BK; kk++) {
            float a[4], b[4];
            *(float4*)a = *(const float4*)&As[kk][ty << 2];
            *(float4*)b = *(const float4*)&Bs[kk][tx << 2];
#pragma unroll
            for (int i = 0; i < 4; i++)
#pragma unroll
                for (int j = 0; j < 4; j++)
                    acc[i][j] = fmaf(a[i], b[j], acc[i][j]);
        }
    }

    float4 bb = *(const float4*)(bias + cb + (tx << 2));
    float bj[4] = {bb.x, bb.y, bb.z, bb.w};
#pragma unroll
    for (int i = 0; i < 4; i++) {
        float v[4];
#pragma unroll
        for (int j = 0; j < 4; j++) {
            float t = acc[i][j] + bj[j];
            if (RELU) t = fmaxf(t, 0.f);
            v[j] = t;
        }
        float4 c = make_float4(v[0], v[1], v[2], v[3]);
        *(float4*)(Cout + (size_t)(rb + (ty << 2) + i) * DD + cb + (tx << 2)) = c;
    }
}

// ---------------- combine: out[n] = w0*y[pos0] + w1*y[pos1] ----------------
__global__ void combine_kernel(int t0, int T,
                               const float* __restrict__ y,
                               const int* __restrict__ posl,
                               const float* __restrict__ wts,
                               float* __restrict__ out) {
    int idx = blockIdx.x * blockDim.x + threadIdx.x;
    if (idx >= T * (DD / 4)) return;
    int i = idx >> 7;          // token (DD/4 = 128 float4 per row)
    int j = idx & 127;
    int p0 = posl[2 * i], p1 = posl[2 * i + 1];
    float w0 = wts[2 * i], w1 = wts[2 * i + 1];
    float4 a = ((const float4*)(y + (size_t)p0 * DD))[j];
    float4 b = ((const float4*)(y + (size_t)p1 * DD))[j];
    float4 c;
    c.x = w0 * a.x + w1 * b.x;
    c.y = w0 * a.y + w1 * b.y;
    c.z = w0 * a.z + w1 * b.z;
    c.w = w0 * a.w + w1 * b.w;
    ((float4*)(out + (size_t)(t0 + i) * DD))[j] = c;
}

extern "C" void kernel_launch(void* const* d_in, const int* in_sizes, int n_in,
                              void* d_out, int out_size, void* d_ws, size_t ws_size,
                              hipStream_t stream) {
    const float* x  = (const float*)d_in[0];   // [32768,512]
    const float* Wg = (const float*)d_in[1];   // [3,8]
    const float* bg = (const float*)d_in[2];   // [8]
    const float* Wh = (const float*)d_in[3];   // [8,3,512,512]
    const float* bh = (const float*)d_in[4];   // [8,3,512]
    const float* Wo = (const float*)d_in[5];   // [8,512,512]
    const float* bo = (const float*)d_in[6];   // [8,512]
    float* out = (float*)d_out;

    // choose phase size T (tokens per phase) to fit workspace
    int T = NTOK;
    while (T > 64) {
        size_t C = 2 * (size_t)T + 512;
        size_t need = 4096 + 3 * ((size_t)T * 2 * 4) + C * 4 + 512 + 2 * C * DD * 4;
        if (need <= ws_size) break;
        T >>= 1;
    }
    int phases = (NTOK + T - 1) / T;
    size_t C = 2 * (size_t)T + 512;

    char* p = (char*)d_ws;
    int* counts = (int*)p;             // [8]
    int* off    = (int*)(p + 64);      // [9]
    int* cursor = (int*)(p + 128);     // [8]
    char* q = p + 4096;
    int*   eids = (int*)q;    q += (size_t)T * 2 * 4;
    int*   posl = (int*)q;    q += (size_t)T * 2 * 4;
    float* wts  = (float*)q;  q += (size_t)T * 2 * 4;
    int* list_token = (int*)q; q += C * 4;
    q = (char*)(((uintptr_t)q + 255) & ~(uintptr_t)255);
    float* bufA = (float*)q;  q += C * DD * 4;
    float* bufB = (float*)q;

    for (int ph = 0; ph < phases; ph++) {
        int t0 = ph * T;
        int Tc = (NTOK - t0 < T) ? (NTOK - t0) : T;

        hipMemsetAsync(counts, 0, 256, stream);              // counts/off/cursor
        hipMemsetAsync(list_token, 0xFF, C * 4, stream);     // -1 padding rows

        route_kernel<<<(Tc + 255) / 256, 256, 0, stream>>>(x, Wg, bg, t0, Tc,
                                                           counts, eids, wts);
        offsets_kernel<<<1, 64, 0, stream>>>(counts, off, cursor);
        scatter_kernel<<<(Tc + 255) / 256, 256, 0, stream>>>(t0, Tc, eids, cursor,
                                                             list_token, posl);

        dim3 g((unsigned)(C / BM), DD / BN);
        // layer 0: gather rows from x, Wh[e,0], relu
        mlp_gemm<true, true><<<g, 256, 0, stream>>>(
            x, list_token, Wh, 3 * DD * DD, bh, 3 * DD, off, bufA);
        // layer 1: Wh[e,1], relu
        mlp_gemm<false, true><<<g, 256, 0, stream>>>(
            bufA, nullptr, Wh + (size_t)DD * DD, 3 * DD * DD, bh + DD, 3 * DD, off, bufB);
        // layer 2: Wh[e,2], relu
        mlp_gemm<false, true><<<g, 256, 0, stream>>>(
            bufB, nullptr, Wh + (size_t)2 * DD * DD, 3 * DD * DD, bh + 2 * DD, 3 * DD, off, bufA);
        // output layer: Wo[e], no relu
        mlp_gemm<false, false><<<g, 256, 0, stream>>>(
            bufA, nullptr, Wo, DD * DD, bo, DD, off, bufB);

        combine_kernel<<<((size_t)Tc * (DD / 4) + 255) / 256, 256, 0, stream>>>(
            t0, Tc, bufB, posl, wts, out);
    }
}

// Round 2
// 1431.491 us; speedup vs baseline: 1.7981x; 1.7981x over previous
//
#include <hip/hip_runtime.h>
#include <cstdint>
#include <cstddef>

#define DD   512
#define NTOK 32768
#define NE   8
#define BM   128
#define BN   128
#define BK   32
#define LDK  40   // padded LDS row (elements): 80 B, multiple of 16 B

typedef unsigned int  u32;
typedef unsigned short u16;
using bf16x8 = __attribute__((ext_vector_type(8))) short;
using f32x4  = __attribute__((ext_vector_type(4))) float;

__device__ __forceinline__ u32 rne_bf16(float f) {
    u32 u = __float_as_uint(f);
    return (u + 0x7FFFu + ((u >> 16) & 1u)) >> 16;
}
__device__ __forceinline__ void split1(float f, u16& h, u16& l) {
    u32 hb = rne_bf16(f);
    float hf = __uint_as_float(hb << 16);
    float r = f - hf;
    u32 lb = rne_bf16(r);
    h = (u16)hb; l = (u16)lb;
}
__device__ __forceinline__ void split8(const float4& a, const float4& b,
                                       uint4& H, uint4& L) {
    float fs[8] = {a.x, a.y, a.z, a.w, b.x, b.y, b.z, b.w};
    u16 hs[8], ls[8];
#pragma unroll
    for (int i = 0; i < 8; i++) split1(fs[i], hs[i], ls[i]);
    H.x = hs[0] | ((u32)hs[1] << 16); H.y = hs[2] | ((u32)hs[3] << 16);
    H.z = hs[4] | ((u32)hs[5] << 16); H.w = hs[6] | ((u32)hs[7] << 16);
    L.x = ls[0] | ((u32)ls[1] << 16); L.y = ls[2] | ((u32)ls[3] << 16);
    L.z = ls[4] | ((u32)ls[5] << 16); L.w = ls[6] | ((u32)ls[7] << 16);
}

// ---------------- routing ----------------
__global__ void route_kernel(const float* __restrict__ x,
                             const float* __restrict__ Wg,
                             const float* __restrict__ bg,
                             int t0, int T,
                             int* __restrict__ counts,
                             int* __restrict__ eids,
                             float* __restrict__ wts) {
    int i = blockIdx.x * blockDim.x + threadIdx.x;
    if (i >= T) return;
    int n = t0 + i;
    const float* xr = x + (size_t)n * DD + (DD - 3);
    float x0 = xr[0], x1 = xr[1], x2 = xr[2];
    float g[NE];
#pragma unroll
    for (int e = 0; e < NE; e++)
        g[e] = x0 * Wg[e] + x1 * Wg[NE + e] + x2 * Wg[2 * NE + e] + bg[e];
    int e0 = 0; float v0 = g[0];
#pragma unroll
    for (int e = 1; e < NE; e++) if (g[e] > v0) { v0 = g[e]; e0 = e; }
    int e1 = -1; float v1 = -3.0e38f;
#pragma unroll
    for (int e = 0; e < NE; e++) if (e != e0 && g[e] > v1) { v1 = g[e]; e1 = e; }
    float t = expf(v1 - v0);
    float s = 1.0f / (1.0f + t);
    eids[2 * i] = e0; eids[2 * i + 1] = e1;
    wts[2 * i] = s;  wts[2 * i + 1] = t * s;
    atomicAdd(&counts[e0], 1);
    atomicAdd(&counts[e1], 1);
}

__global__ void offsets_kernel(const int* __restrict__ counts,
                               int* __restrict__ off,
                               int* __restrict__ cursor) {
    if (threadIdx.x == 0) {
        int acc = 0;
        for (int e = 0; e < NE; e++) {
            off[e] = acc;
            cursor[e] = acc;
            acc += (counts[e] + (BM - 1)) & ~(BM - 1);   // pad to 128 rows
        }
        off[NE] = acc;
    }
}

__global__ void scatter_kernel(int t0, int T,
                               const int* __restrict__ eids,
                               int* __restrict__ cursor,
                               int* __restrict__ list_token,
                               int* __restrict__ posl) {
    int i = blockIdx.x * blockDim.x + threadIdx.x;
    if (i >= T) return;
#pragma unroll
    for (int k = 0; k < 2; k++) {
        int e = eids[2 * i + k];
        int p = atomicAdd(&cursor[e], 1);
        list_token[p] = t0 + i;
        posl[2 * i + k] = p;
    }
}

// ---------------- weight transpose + hi/lo split ----------------
// Wh[e][l][k][n] (l<3) / Wo[e][k][n]  ->  Wt{Hi,Lo}[(e*4+l)][n][k]
__global__ void convert_w(const float* __restrict__ Wh,
                          const float* __restrict__ Wo,
                          u16* __restrict__ WtHi, u16* __restrict__ WtLo) {
    __shared__ float tile[32][33];
    int z = blockIdx.z;             // e*4 + l
    int e = z >> 2, l = z & 3;
    const float* src = (l < 3) ? (Wh + ((size_t)e * 3 + l) * DD * DD)
                               : (Wo + (size_t)e * DD * DD);
    int bx = blockIdx.x, by = blockIdx.y;   // n-tile, k-tile
    int tx = threadIdx.x, ty = threadIdx.y; // 32 x 8
#pragma unroll
    for (int j = 0; j < 4; j++)
        tile[ty + j * 8][tx] = src[(size_t)(by * 32 + ty + j * 8) * DD + bx * 32 + tx];
    __syncthreads();
    u16* dh = WtHi + (size_t)z * DD * DD;
    u16* dl = WtLo + (size_t)z * DD * DD;
#pragma unroll
    for (int j = 0; j < 4; j++) {
        int n = bx * 32 + ty + j * 8;
        int k = by * 32 + tx;
        u16 h, lo;
        split1(tile[tx][ty + j * 8], h, lo);
        dh[(size_t)n * DD + k] = h;
        dl[(size_t)n * DD + k] = lo;
    }
}

// ---------------- split-bf16 MFMA GEMM ----------------
template <bool GATHER, bool RELU, bool OUTF32>
__global__ __launch_bounds__(256, 2) void moe_gemm(
    const float* __restrict__ Xf,
    const u16* __restrict__ Ahi, const u16* __restrict__ Alo,
    const int* __restrict__ list_token,
    const u16* __restrict__ WtHi, const u16* __restrict__ WtLo,
    int layer,
    const float* __restrict__ bptr, int bestride,
    const int* __restrict__ off,
    u16* __restrict__ Chi, u16* __restrict__ Clo,
    float* __restrict__ Cf)
{
    int rb = blockIdx.x * BM;
    if (rb >= off[NE]) return;
    int e = 0;
#pragma unroll
    for (int q = 1; q < NE; q++) if (rb >= off[q]) e = q;
    int cb = blockIdx.y * BN;

    __shared__ u16 Ah[BM][LDK], Al[BM][LDK], Bh[BN][LDK], Bl[BN][LDK];

    int tid = threadIdx.x;
    int srow = tid >> 1;          // 0..127
    int shalf = tid & 1;          // k sub-chunk of 16

    const size_t wbase = ((size_t)e * 4 + layer) * (size_t)DD * DD;
    const u16* bhp = WtHi + wbase + (size_t)(cb + srow) * DD + shalf * 16;
    const u16* blp = WtLo + wbase + (size_t)(cb + srow) * DD + shalf * 16;

    const float* af = nullptr;
    const u16 *ahp = nullptr, *alp = nullptr;
    bool avalid = true;
    if (GATHER) {
        int r = list_token[rb + srow];
        avalid = (r >= 0);
        af = Xf + (size_t)(avalid ? r : 0) * DD + shalf * 16;
    } else {
        ahp = Ahi + (size_t)(rb + srow) * DD + shalf * 16;
        alp = Alo + (size_t)(rb + srow) * DD + shalf * 16;
    }

    int lane = tid & 63;
    int wv = tid >> 6;
    int wr = (wv >> 1) * 64;      // wave row offset
    int wc = (wv & 1) * 64;       // wave col offset
    int lrow = lane & 15, lg = lane >> 4;

    f32x4 acc[4][4];
#pragma unroll
    for (int i = 0; i < 4; i++)
#pragma unroll
        for (int j = 0; j < 4; j++) acc[i][j] = (f32x4){0.f, 0.f, 0.f, 0.f};

    for (int k0 = 0; k0 < DD; k0 += BK) {
        uint4 vah0, vah1, val0, val1;
        if (GATHER) {
            float4 f0 = {0,0,0,0}, f1 = {0,0,0,0}, f2 = {0,0,0,0}, f3 = {0,0,0,0};
            if (avalid) {
                const float4* fp = (const float4*)(af + k0);
                f0 = fp[0]; f1 = fp[1]; f2 = fp[2]; f3 = fp[3];
            }
            split8(f0, f1, vah0, val0);
            split8(f2, f3, vah1, val1);
        } else {
            vah0 = *(const uint4*)(ahp + k0);     vah1 = *(const uint4*)(ahp + k0 + 8);
            val0 = *(const uint4*)(alp + k0);     val1 = *(const uint4*)(alp + k0 + 8);
        }
        uint4 vbh0 = *(const uint4*)(bhp + k0),  vbh1 = *(const uint4*)(bhp + k0 + 8);
        uint4 vbl0 = *(const uint4*)(blp + k0),  vbl1 = *(const uint4*)(blp + k0 + 8);

        __syncthreads();
        *(uint4*)&Ah[srow][shalf * 16]     = vah0;
        *(uint4*)&Ah[srow][shalf * 16 + 8] = vah1;
        *(uint4*)&Al[srow][shalf * 16]     = val0;
        *(uint4*)&Al[srow][shalf * 16 + 8] = val1;
        *(uint4*)&Bh[srow][shalf * 16]     = vbh0;
        *(uint4*)&Bh[srow][shalf * 16 + 8] = vbh1;
        *(uint4*)&Bl[srow][shalf * 16]     = vbl0;
        *(uint4*)&Bl[srow][shalf * 16 + 8] = vbl1;
        __syncthreads();

        bf16x8 ah[4], al[4];
#pragma unroll
        for (int mi = 0; mi < 4; mi++) {
            ah[mi] = *(const bf16x8*)&Ah[wr + mi * 16 + lrow][lg * 8];
            al[mi] = *(const bf16x8*)&Al[wr + mi * 16 + lrow][lg * 8];
        }
#pragma unroll
        for (int ni = 0; ni < 4; ni++) {
            bf16x8 bh_ = *(const bf16x8*)&Bh[wc + ni * 16 + lrow][lg * 8];
            bf16x8 bl_ = *(const bf16x8*)&Bl[wc + ni * 16 + lrow][lg * 8];
#pragma unroll
            for (int mi = 0; mi < 4; mi++) {
                acc[mi][ni] = __builtin_amdgcn_mfma_f32_16x16x32_bf16(ah[mi], bh_, acc[mi][ni], 0, 0, 0);
                acc[mi][ni] = __builtin_amdgcn_mfma_f32_16x16x32_bf16(al[mi], bh_, acc[mi][ni], 0, 0, 0);
                acc[mi][ni] = __builtin_amdgcn_mfma_f32_16x16x32_bf16(ah[mi], bl_, acc[mi][ni], 0, 0, 0);
            }
        }
    }

    // epilogue: bias (+relu); write fp32 or hi/lo bf16
#pragma unroll
    for (int ni = 0; ni < 4; ni++) {
        int col = cb + wc + ni * 16 + lrow;
        float bb = bptr[e * bestride + col];
#pragma unroll
        for (int mi = 0; mi < 4; mi++) {
            int row0 = rb + wr + mi * 16 + lg * 4;
#pragma unroll
            for (int r = 0; r < 4; r++) {
                float v = acc[mi][ni][r] + bb;
                if (RELU) v = fmaxf(v, 0.f);
                size_t idx = (size_t)(row0 + r) * DD + col;
                if (OUTF32) {
                    Cf[idx] = v;
                } else {
                    u16 h, lo;
                    split1(v, h, lo);
                    Chi[idx] = h;
                    Clo[idx] = lo;
                }
            }
        }
    }
}

// ---------------- combine ----------------
__global__ void combine_kernel(int t0, int T,
                               const float* __restrict__ y,
                               const int* __restrict__ posl,
                               const float* __restrict__ wts,
                               float* __restrict__ out) {
    int idx = blockIdx.x * blockDim.x + threadIdx.x;
    if (idx >= T * (DD / 4)) return;
    int i = idx >> 7;
    int j = idx & 127;
    int p0 = posl[2 * i], p1 = posl[2 * i + 1];
    float w0 = wts[2 * i], w1 = wts[2 * i + 1];
    float4 a = ((const float4*)(y + (size_t)p0 * DD))[j];
    float4 b = ((const float4*)(y + (size_t)p1 * DD))[j];
    float4 c;
    c.x = w0 * a.x + w1 * b.x;
    c.y = w0 * a.y + w1 * b.y;
    c.z = w0 * a.z + w1 * b.z;
    c.w = w0 * a.w + w1 * b.w;
    ((float4*)(out + (size_t)(t0 + i) * DD))[j] = c;
}

extern "C" void kernel_launch(void* const* d_in, const int* in_sizes, int n_in,
                              void* d_out, int out_size, void* d_ws, size_t ws_size,
                              hipStream_t stream) {
    const float* x  = (const float*)d_in[0];
    const float* Wg = (const float*)d_in[1];
    const float* bg = (const float*)d_in[2];
    const float* Wh = (const float*)d_in[3];
    const float* bh = (const float*)d_in[4];
    const float* bo = (const float*)d_in[6];
    const float* Wo = (const float*)d_in[5];
    float* out = (float*)d_out;

    const size_t WT_ELEMS = (size_t)NE * 4 * DD * DD;     // 8.39M
    // pick phase size T to fit workspace
    int T = NTOK;
    while (T > 64) {
        size_t C = 2 * (size_t)T + NE * BM;
        size_t need = 4096 + 2 * WT_ELEMS * 2 + 3 * ((size_t)T * 2 * 4)
                    + C * 4 + 512 + 4 * (C * (size_t)DD * 2);
        if (need <= ws_size) break;
        T >>= 1;
    }
    int phases = (NTOK + T - 1) / T;
    size_t C = 2 * (size_t)T + NE * BM;

    char* p = (char*)d_ws;
    int* counts = (int*)p;
    int* off    = (int*)(p + 64);
    int* cursor = (int*)(p + 128);
    char* q = p + 4096;
    u16* WtHi = (u16*)q;  q += WT_ELEMS * 2;
    u16* WtLo = (u16*)q;  q += WT_ELEMS * 2;
    int* eids = (int*)q;  q += (size_t)T * 2 * 4;
    int* posl = (int*)q;  q += (size_t)T * 2 * 4;
    float* wts = (float*)q; q += (size_t)T * 2 * 4;
    int* list_token = (int*)q; q += C * 4;
    q = (char*)(((uintptr_t)q + 255) & ~(uintptr_t)255);
    u16* bufA_hi = (u16*)q; q += C * DD * 2;
    u16* bufA_lo = (u16*)q; q += C * DD * 2;
    u16* bufB_hi = (u16*)q; q += C * DD * 2;   // final fp32 y aliases hi+lo
    u16* bufB_lo = (u16*)q; q += C * DD * 2;
    float* yf = (float*)bufB_hi;

    // weight transpose + split (once per call)
    convert_w<<<dim3(16, 16, 32), dim3(32, 8), 0, stream>>>(Wh, Wo, WtHi, WtLo);

    for (int ph = 0; ph < phases; ph++) {
        int t0 = ph * T;
        int Tc = (NTOK - t0 < T) ? (NTOK - t0) : T;

        hipMemsetAsync(counts, 0, 256, stream);
        hipMemsetAsync(list_token, 0xFF, C * 4, stream);

        route_kernel<<<(Tc + 255) / 256, 256, 0, stream>>>(x, Wg, bg, t0, Tc,
                                                           counts, eids, wts);
        offsets_kernel<<<1, 64, 0, stream>>>(counts, off, cursor);
        scatter_kernel<<<(Tc + 255) / 256, 256, 0, stream>>>(t0, Tc, eids, cursor,
                                                             list_token, posl);

        dim3 g((unsigned)(C / BM), DD / BN);
        // layer 0: gather fp32 x -> bufA (hi/lo)
        moe_gemm<true, true, false><<<g, 256, 0, stream>>>(
            x, nullptr, nullptr, list_token, WtHi, WtLo, 0,
            bh, 3 * DD, off, bufA_hi, bufA_lo, nullptr);
        // layer 1: bufA -> bufB
        moe_gemm<false, true, false><<<g, 256, 0, stream>>>(
            nullptr, bufA_hi, bufA_lo, nullptr, WtHi, WtLo, 1,
            bh + DD, 3 * DD, off, bufB_hi, bufB_lo, nullptr);
        // layer 2: bufB -> bufA
        moe_gemm<false, true, false><<<g, 256, 0, stream>>>(
            nullptr, bufB_hi, bufB_lo, nullptr, WtHi, WtLo, 2,
            bh + 2 * DD, 3 * DD, off, bufA_hi, bufA_lo, nullptr);
        // layer 3 (output): bufA -> yf (fp32)
        moe_gemm<false, false, true><<<g, 256, 0, stream>>>(
            nullptr, bufA_hi, bufA_lo, nullptr, WtHi, WtLo, 3,
            bo, DD, off, nullptr, nullptr, yf);

        combine_kernel<<<((size_t)Tc * (DD / 4) + 255) / 256, 256, 0, stream>>>(
            t0, Tc, yf, posl, wts, out);
    }
}

// Round 3
// 768.237 us; speedup vs baseline: 3.3505x; 1.8633x over previous
//
#include <hip/hip_runtime.h>
#include <cstdint>
#include <cstddef>

#define DD   512
#define NTOK 32768
#define NE   8
#define BM   128
#define BN   128
#define BK   32
#define LDK  40   // padded LDS row (elements): 80 B, multiple of 16 B
#define RBLK 1024 // routing/scatter block size

typedef unsigned int  u32;
typedef unsigned short u16;
typedef unsigned long long u64;
using bf16x8 = __attribute__((ext_vector_type(8))) short;
using f32x4  = __attribute__((ext_vector_type(4))) float;

__device__ __forceinline__ u32 rne_bf16(float f) {
    u32 u = __float_as_uint(f);
    return (u + 0x7FFFu + ((u >> 16) & 1u)) >> 16;
}
__device__ __forceinline__ void split1(float f, u16& h, u16& l) {
    u32 hb = rne_bf16(f);
    float hf = __uint_as_float(hb << 16);
    float r = f - hf;
    u32 lb = rne_bf16(r);
    h = (u16)hb; l = (u16)lb;
}
__device__ __forceinline__ void split8(const float4& a, const float4& b,
                                       uint4& H, uint4& L) {
    float fs[8] = {a.x, a.y, a.z, a.w, b.x, b.y, b.z, b.w};
    u16 hs[8], ls[8];
#pragma unroll
    for (int i = 0; i < 8; i++) split1(fs[i], hs[i], ls[i]);
    H.x = hs[0] | ((u32)hs[1] << 16); H.y = hs[2] | ((u32)hs[3] << 16);
    H.z = hs[4] | ((u32)hs[5] << 16); H.w = hs[6] | ((u32)hs[7] << 16);
    L.x = ls[0] | ((u32)ls[1] << 16); L.y = ls[2] | ((u32)ls[3] << 16);
    L.z = ls[4] | ((u32)ls[5] << 16); L.w = ls[6] | ((u32)ls[7] << 16);
}

// ---------------- routing: gates -> top2 -> softmax; block-aggregated counts ----------------
__global__ __launch_bounds__(RBLK) void route_kernel(
    const float* __restrict__ x,
    const float* __restrict__ Wg,
    const float* __restrict__ bg,
    int t0, int T,
    int* __restrict__ counts,
    int* __restrict__ eids,
    float* __restrict__ wts) {
    __shared__ int lcnt[NE];
    int tid = threadIdx.x;
    if (tid < NE) lcnt[tid] = 0;
    __syncthreads();

    int i = blockIdx.x * RBLK + tid;
    bool active = (i < T);
    int e0 = 0, e1 = 0;
    if (active) {
        int n = t0 + i;
        const float* xr = x + (size_t)n * DD + (DD - 3);
        float x0 = xr[0], x1 = xr[1], x2 = xr[2];
        float g[NE];
#pragma unroll
        for (int e = 0; e < NE; e++)
            g[e] = x0 * Wg[e] + x1 * Wg[NE + e] + x2 * Wg[2 * NE + e] + bg[e];
        float v0 = g[0];
#pragma unroll
        for (int e = 1; e < NE; e++) if (g[e] > v0) { v0 = g[e]; e0 = e; }
        float v1 = -3.0e38f; e1 = -1;
#pragma unroll
        for (int e = 0; e < NE; e++) if (e != e0 && g[e] > v1) { v1 = g[e]; e1 = e; }
        float t = expf(v1 - v0);
        float s = 1.0f / (1.0f + t);
        eids[2 * i] = e0; eids[2 * i + 1] = e1;
        wts[2 * i] = s;  wts[2 * i + 1] = t * s;
    }

    int lane = tid & 63;
#pragma unroll
    for (int k = 0; k < 2; k++) {
        int e = active ? (k ? e1 : e0) : -1;
#pragma unroll
        for (int ex = 0; ex < NE; ex++) {
            u64 m = __ballot(e == ex);
            if (m && lane == 0) atomicAdd(&lcnt[ex], __popcll(m));
        }
    }
    __syncthreads();
    if (tid < NE && lcnt[tid]) atomicAdd(&counts[tid], lcnt[tid]);
}

// ---------------- padded prefix sum ----------------
__global__ void offsets_kernel(const int* __restrict__ counts,
                               int* __restrict__ off,
                               int* __restrict__ cursor) {
    if (threadIdx.x == 0) {
        int acc = 0;
        for (int e = 0; e < NE; e++) {
            off[e] = acc;
            cursor[e] = acc;
            acc += (counts[e] + (BM - 1)) & ~(BM - 1);
        }
        off[NE] = acc;
    }
}

// ---------------- scatter: block/wave-aggregated position assignment ----------------
__global__ __launch_bounds__(RBLK) void scatter_kernel(
    int t0, int T,
    const int* __restrict__ eids,
    int* __restrict__ cursor,
    int* __restrict__ list_token,
    int* __restrict__ posl) {
    __shared__ int lcnt[NE], lbase[NE];
    __shared__ int woff[RBLK / 64][NE];
    int tid = threadIdx.x, lane = tid & 63, wv = tid >> 6;
    int i = blockIdx.x * RBLK + tid;
    bool active = (i < T);
    u64 lmask = (1ull << lane) - 1ull;

#pragma unroll
    for (int k = 0; k < 2; k++) {
        if (tid < NE) lcnt[tid] = 0;
        __syncthreads();
        int e = active ? eids[2 * i + k] : -1;
        u64 mymask = 0;
#pragma unroll
        for (int ex = 0; ex < NE; ex++) {
            u64 m = __ballot(e == ex);
            if (e == ex) mymask = m;
            if (m && lane == 0) woff[wv][ex] = atomicAdd(&lcnt[ex], __popcll(m));
        }
        __syncthreads();
        if (tid < NE) lbase[tid] = lcnt[tid] ? atomicAdd(&cursor[tid], lcnt[tid]) : 0;
        __syncthreads();
        if (active) {
            int p = lbase[e] + woff[wv][e] + __popcll(mymask & lmask);
            list_token[p] = t0 + i;
            posl[2 * i + k] = p;
        }
        __syncthreads();
    }
}

// ---------------- weight transpose + hi/lo split ----------------
__global__ void convert_w(const float* __restrict__ Wh,
                          const float* __restrict__ Wo,
                          u16* __restrict__ WtHi, u16* __restrict__ WtLo) {
    __shared__ float tile[32][33];
    int z = blockIdx.z;             // e*4 + l
    int e = z >> 2, l = z & 3;
    const float* src = (l < 3) ? (Wh + ((size_t)e * 3 + l) * DD * DD)
                               : (Wo + (size_t)e * DD * DD);
    int bx = blockIdx.x, by = blockIdx.y;   // n-tile, k-tile
    int tx = threadIdx.x, ty = threadIdx.y; // 32 x 8
#pragma unroll
    for (int j = 0; j < 4; j++)
        tile[ty + j * 8][tx] = src[(size_t)(by * 32 + ty + j * 8) * DD + bx * 32 + tx];
    __syncthreads();
    u16* dh = WtHi + (size_t)z * DD * DD;
    u16* dl = WtLo + (size_t)z * DD * DD;
#pragma unroll
    for (int j = 0; j < 4; j++) {
        int n = bx * 32 + ty + j * 8;
        int k = by * 32 + tx;
        u16 h, lo;
        split1(tile[tx][ty + j * 8], h, lo);
        dh[(size_t)n * DD + k] = h;
        dl[(size_t)n * DD + k] = lo;
    }
}

// ---------------- split-bf16 MFMA GEMM ----------------
template <bool GATHER, bool RELU, bool OUTF32>
__global__ __launch_bounds__(256, 2) void moe_gemm(
    const float* __restrict__ Xf,
    const u16* __restrict__ Ahi, const u16* __restrict__ Alo,
    const int* __restrict__ list_token,
    const u16* __restrict__ WtHi, const u16* __restrict__ WtLo,
    int layer,
    const float* __restrict__ bptr, int bestride,
    const int* __restrict__ off,
    u16* __restrict__ Chi, u16* __restrict__ Clo,
    float* __restrict__ Cf)
{
    int rb = blockIdx.x * BM;
    if (rb >= off[NE]) return;
    int e = 0;
#pragma unroll
    for (int q = 1; q < NE; q++) if (rb >= off[q]) e = q;
    int cb = blockIdx.y * BN;

    __shared__ u16 Ah[BM][LDK], Al[BM][LDK], Bh[BN][LDK], Bl[BN][LDK];

    int tid = threadIdx.x;
    int srow = tid >> 1;          // 0..127
    int shalf = tid & 1;          // k sub-chunk of 16

    const size_t wbase = ((size_t)e * 4 + layer) * (size_t)DD * DD;
    const u16* bhp = WtHi + wbase + (size_t)(cb + srow) * DD + shalf * 16;
    const u16* blp = WtLo + wbase + (size_t)(cb + srow) * DD + shalf * 16;

    const float* af = nullptr;
    const u16 *ahp = nullptr, *alp = nullptr;
    bool avalid = true;
    if (GATHER) {
        int r = list_token[rb + srow];
        avalid = (r >= 0);
        af = Xf + (size_t)(avalid ? r : 0) * DD + shalf * 16;
    } else {
        ahp = Ahi + (size_t)(rb + srow) * DD + shalf * 16;
        alp = Alo + (size_t)(rb + srow) * DD + shalf * 16;
    }

    int lane = tid & 63;
    int wv = tid >> 6;
    int wr = (wv >> 1) * 64;      // wave row offset
    int wc = (wv & 1) * 64;       // wave col offset
    int lrow = lane & 15, lg = lane >> 4;

    f32x4 acc[4][4];
#pragma unroll
    for (int i = 0; i < 4; i++)
#pragma unroll
        for (int j = 0; j < 4; j++) acc[i][j] = (f32x4){0.f, 0.f, 0.f, 0.f};

    for (int k0 = 0; k0 < DD; k0 += BK) {
        uint4 vah0, vah1, val0, val1;
        if (GATHER) {
            float4 f0 = {0,0,0,0}, f1 = {0,0,0,0}, f2 = {0,0,0,0}, f3 = {0,0,0,0};
            if (avalid) {
                const float4* fp = (const float4*)(af + k0);
                f0 = fp[0]; f1 = fp[1]; f2 = fp[2]; f3 = fp[3];
            }
            split8(f0, f1, vah0, val0);
            split8(f2, f3, vah1, val1);
        } else {
            vah0 = *(const uint4*)(ahp + k0);     vah1 = *(const uint4*)(ahp + k0 + 8);
            val0 = *(const uint4*)(alp + k0);     val1 = *(const uint4*)(alp + k0 + 8);
        }
        uint4 vbh0 = *(const uint4*)(bhp + k0),  vbh1 = *(const uint4*)(bhp + k0 + 8);
        uint4 vbl0 = *(const uint4*)(blp + k0),  vbl1 = *(const uint4*)(blp + k0 + 8);

        __syncthreads();
        *(uint4*)&Ah[srow][shalf * 16]     = vah0;
        *(uint4*)&Ah[srow][shalf * 16 + 8] = vah1;
        *(uint4*)&Al[srow][shalf * 16]     = val0;
        *(uint4*)&Al[srow][shalf * 16 + 8] = val1;
        *(uint4*)&Bh[srow][shalf * 16]     = vbh0;
        *(uint4*)&Bh[srow][shalf * 16 + 8] = vbh1;
        *(uint4*)&Bl[srow][shalf * 16]     = vbl0;
        *(uint4*)&Bl[srow][shalf * 16 + 8] = vbl1;
        __syncthreads();

        bf16x8 ah[4], al[4];
#pragma unroll
        for (int mi = 0; mi < 4; mi++) {
            ah[mi] = *(const bf16x8*)&Ah[wr + mi * 16 + lrow][lg * 8];
            al[mi] = *(const bf16x8*)&Al[wr + mi * 16 + lrow][lg * 8];
        }
#pragma unroll
        for (int ni = 0; ni < 4; ni++) {
            bf16x8 bh_ = *(const bf16x8*)&Bh[wc + ni * 16 + lrow][lg * 8];
            bf16x8 bl_ = *(const bf16x8*)&Bl[wc + ni * 16 + lrow][lg * 8];
#pragma unroll
            for (int mi = 0; mi < 4; mi++) {
                acc[mi][ni] = __builtin_amdgcn_mfma_f32_16x16x32_bf16(ah[mi], bh_, acc[mi][ni], 0, 0, 0);
                acc[mi][ni] = __builtin_amdgcn_mfma_f32_16x16x32_bf16(al[mi], bh_, acc[mi][ni], 0, 0, 0);
                acc[mi][ni] = __builtin_amdgcn_mfma_f32_16x16x32_bf16(ah[mi], bl_, acc[mi][ni], 0, 0, 0);
            }
        }
    }

    // epilogue: bias (+relu); write fp32 or hi/lo bf16
#pragma unroll
    for (int ni = 0; ni < 4; ni++) {
        int col = cb + wc + ni * 16 + lrow;
        float bb = bptr[e * bestride + col];
#pragma unroll
        for (int mi = 0; mi < 4; mi++) {
            int row0 = rb + wr + mi * 16 + lg * 4;
#pragma unroll
            for (int r = 0; r < 4; r++) {
                float v = acc[mi][ni][r] + bb;
                if (RELU) v = fmaxf(v, 0.f);
                size_t idx = (size_t)(row0 + r) * DD + col;
                if (OUTF32) {
                    Cf[idx] = v;
                } else {
                    u16 h, lo;
                    split1(v, h, lo);
                    Chi[idx] = h;
                    Clo[idx] = lo;
                }
            }
        }
    }
}

// ---------------- combine ----------------
__global__ void combine_kernel(int t0, int T,
                               const float* __restrict__ y,
                               const int* __restrict__ posl,
                               const float* __restrict__ wts,
                               float* __restrict__ out) {
    int idx = blockIdx.x * blockDim.x + threadIdx.x;
    if (idx >= T * (DD / 4)) return;
    int i = idx >> 7;
    int j = idx & 127;
    int p0 = posl[2 * i], p1 = posl[2 * i + 1];
    float w0 = wts[2 * i], w1 = wts[2 * i + 1];
    float4 a = ((const float4*)(y + (size_t)p0 * DD))[j];
    float4 b = ((const float4*)(y + (size_t)p1 * DD))[j];
    float4 c;
    c.x = w0 * a.x + w1 * b.x;
    c.y = w0 * a.y + w1 * b.y;
    c.z = w0 * a.z + w1 * b.z;
    c.w = w0 * a.w + w1 * b.w;
    ((float4*)(out + (size_t)(t0 + i) * DD))[j] = c;
}

extern "C" void kernel_launch(void* const* d_in, const int* in_sizes, int n_in,
                              void* d_out, int out_size, void* d_ws, size_t ws_size,
                              hipStream_t stream) {
    const float* x  = (const float*)d_in[0];
    const float* Wg = (const float*)d_in[1];
    const float* bg = (const float*)d_in[2];
    const float* Wh = (const float*)d_in[3];
    const float* bh = (const float*)d_in[4];
    const float* Wo = (const float*)d_in[5];
    const float* bo = (const float*)d_in[6];
    float* out = (float*)d_out;

    const size_t WT_ELEMS = (size_t)NE * 4 * DD * DD;     // 8.39M
    // pick phase size T to fit workspace
    int T = NTOK;
    while (T > 64) {
        size_t C = 2 * (size_t)T + NE * BM;
        size_t need = 4096 + 2 * WT_ELEMS * 2 + 3 * ((size_t)T * 2 * 4)
                    + C * 4 + 512 + 4 * (C * (size_t)DD * 2);
        if (need <= ws_size) break;
        T >>= 1;
    }
    int phases = (NTOK + T - 1) / T;
    size_t C = 2 * (size_t)T + NE * BM;

    char* p = (char*)d_ws;
    int* counts = (int*)p;
    int* off    = (int*)(p + 64);
    int* cursor = (int*)(p + 128);
    char* q = p + 4096;
    u16* WtHi = (u16*)q;  q += WT_ELEMS * 2;
    u16* WtLo = (u16*)q;  q += WT_ELEMS * 2;
    int* eids = (int*)q;  q += (size_t)T * 2 * 4;
    int* posl = (int*)q;  q += (size_t)T * 2 * 4;
    float* wts = (float*)q; q += (size_t)T * 2 * 4;
    int* list_token = (int*)q; q += C * 4;
    q = (char*)(((uintptr_t)q + 255) & ~(uintptr_t)255);
    u16* bufA_hi = (u16*)q; q += C * DD * 2;
    u16* bufA_lo = (u16*)q; q += C * DD * 2;
    u16* bufB_hi = (u16*)q; q += C * DD * 2;   // final fp32 y aliases hi+lo
    u16* bufB_lo = (u16*)q; q += C * DD * 2;
    float* yf = (float*)bufB_hi;

    // weight transpose + split (once per call)
    convert_w<<<dim3(16, 16, 32), dim3(32, 8), 0, stream>>>(Wh, Wo, WtHi, WtLo);

    for (int ph = 0; ph < phases; ph++) {
        int t0 = ph * T;
        int Tc = (NTOK - t0 < T) ? (NTOK - t0) : T;

        hipMemsetAsync(counts, 0, 256, stream);
        hipMemsetAsync(list_token, 0xFF, C * 4, stream);

        route_kernel<<<(Tc + RBLK - 1) / RBLK, RBLK, 0, stream>>>(
            x, Wg, bg, t0, Tc, counts, eids, wts);
        offsets_kernel<<<1, 64, 0, stream>>>(counts, off, cursor);
        scatter_kernel<<<(Tc + RBLK - 1) / RBLK, RBLK, 0, stream>>>(
            t0, Tc, eids, cursor, list_token, posl);

        dim3 g((unsigned)(C / BM), DD / BN);
        // layer 0: gather fp32 x -> bufA (hi/lo)
        moe_gemm<true, true, false><<<g, 256, 0, stream>>>(
            x, nullptr, nullptr, list_token, WtHi, WtLo, 0,
            bh, 3 * DD, off, bufA_hi, bufA_lo, nullptr);
        // layer 1: bufA -> bufB
        moe_gemm<false, true, false><<<g, 256, 0, stream>>>(
            nullptr, bufA_hi, bufA_lo, nullptr, WtHi, WtLo, 1,
            bh + DD, 3 * DD, off, bufB_hi, bufB_lo, nullptr);
        // layer 2: bufB -> bufA
        moe_gemm<false, true, false><<<g, 256, 0, stream>>>(
            nullptr, bufB_hi, bufB_lo, nullptr, WtHi, WtLo, 2,
            bh + 2 * DD, 3 * DD, off, bufA_hi, bufA_lo, nullptr);
        // layer 3 (output): bufA -> yf (fp32)
        moe_gemm<false, false, true><<<g, 256, 0, stream>>>(
            nullptr, bufA_hi, bufA_lo, nullptr, WtHi, WtLo, 3,
            bo, DD, off, nullptr, nullptr, yf);

        combine_kernel<<<((size_t)Tc * (DD / 4) + 255) / 256, 256, 0, stream>>>(
            t0, Tc, yf, posl, wts, out);
    }
}